// Round 25
// baseline (204.663 us; speedup 1.0000x reference)
//
#include <hip/hip_runtime.h>
#include <stdint.h>
#include <limits.h>

// VERIFIED SEMANTICS (r16, absmax=0):
//  - GRID from module-level numpy f32 floor-divide: (704, 799, 39)
//  - keys: f32 sub, * 10.0f (XLA reciprocal of 0.1f), floorf, cast
//  - scatter-add drops OOB keys; gather clamps; tie-break = key ascending
#define GYZ 31161          // 799*39
#define GY_K 799
#define GZ_K 39
#define KCELLS 21937344    // 704 * 799 * 39
#define MAXV 20000
#define MAXP 32

#define NCLS 32
#define CANDCAP 524288
#define CAND2CAP 1048576
#define KEYMASK 0x1FFFFFFu // 2^25-1; KCELLS < 2^25
#define LCAP 4096
#define TSIZE 65536        // hash table slots (u64), load 0.3
#define TMASK 65535
#define TEMPTY 0xFFFFFFFFFFFFFFFFull

#define NB 1024            // partition buckets (cell-space)
#define BUCKSZ 21424       // cells/bucket; NB*BUCKSZ >= KCELLS
#define WPB (BUCKSZ / 4)   // 5356 LDS words (21.4 KB)
#define PCHUNK 16384       // points per partition block (~16/bucket segments)
#define PTH 512
#define PPT (PCHUNK / PTH) // 32 keys per thread in registers
#define DLCAP 1024         // k_bhist per-block cand buffer

#define SB 4096            // s-value ranking buckets (s >> 17)

__device__ __forceinline__ int point_key(float x, float y, float z) {
  int ix = (int)floorf((x - 0.0f) * 10.0f);
  int iy = (int)floorf((y + 40.0f) * 10.0f);
  int iz = (int)floorf((z + 3.0f) * 10.0f);
  return (ix * GY_K + iy) * GZ_K + iz;
}

__device__ __forceinline__ uint32_t keyhash(uint32_t key) {
  return (key * 2654435761u) >> 16;
}

// ---- A: fused keys + block-contiguous partition ----
__global__ __launch_bounds__(512) void k_kp(const float4* __restrict__ pts, int N,
                                            uint32_t* __restrict__ keys,
                                            uint32_t* __restrict__ bkeys,
                                            uint32_t* __restrict__ stable) {
  __shared__ uint32_t sk[PCHUNK];       // 64 KB staging
  __shared__ uint32_t lh[NB], lb[NB], cur[NB];
  __shared__ uint32_t wsum[8];
  int blk = blockIdx.x;
  int c0 = blk * PCHUNK;
  int m = min(PCHUNK, N - c0);
  if (m <= 0) return;
  for (int j = threadIdx.x; j < NB; j += PTH) lh[j] = 0;
  __syncthreads();
  uint32_t kreg[PPT];
#pragma unroll
  for (int j = 0; j < PPT; ++j) {
    int idx = j * PTH + threadIdx.x;    // coalesced
    if (idx < m) {
      float4 p = pts[c0 + idx];
      uint32_t key = (uint32_t)point_key(p.x, p.y, p.z);
      kreg[j] = key;
      keys[c0 + idx] = key;
      atomicAdd(&lh[min(key / BUCKSZ, (uint32_t)(NB - 1))], 1u);
    } else kreg[j] = 0xFFFFFFFFu;
  }
  __syncthreads();
  // exclusive scan over 1024 buckets (2 per thread)
  int t = threadIdx.x;
  uint32_t v0 = lh[2 * t], v1 = lh[2 * t + 1];
  uint32_t s = v0 + v1;
  uint32_t incl = s;
#pragma unroll
  for (int d = 1; d < 64; d <<= 1) {
    uint32_t up = __shfl_up(incl, d);
    if ((t & 63) >= d) incl += up;
  }
  int wave = t >> 6;
  if ((t & 63) == 63) wsum[wave] = incl;
  __syncthreads();
  if (t == 0) {
    uint32_t run = 0;
    for (int w = 0; w < 8; ++w) { uint32_t tmp = wsum[w]; wsum[w] = run; run += tmp; }
  }
  __syncthreads();
  uint32_t excl = wsum[wave] + incl - s;
  lb[2 * t] = excl;          lb[2 * t + 1] = excl + v0;
  cur[2 * t] = excl;         cur[2 * t + 1] = excl + v0;
  size_t tb = (size_t)blk * (NB + 1);
  stable[tb + 2 * t] = (uint32_t)c0 + excl;
  stable[tb + 2 * t + 1] = (uint32_t)c0 + excl + v0;
  if (t == 0) stable[tb + NB] = (uint32_t)(c0 + m);
  __syncthreads();
#pragma unroll
  for (int j = 0; j < PPT; ++j) {
    uint32_t key = kreg[j];
    if (key != 0xFFFFFFFFu) {
      uint32_t b = min(key / BUCKSZ, (uint32_t)(NB - 1));
      sk[atomicAdd(&cur[b], 1u)] = key;
    }
  }
  __syncthreads();
  for (int j = threadIdx.x; j < m; j += PTH) bkeys[c0 + j] = sk[j];  // contiguous
}

// ---- D: per-bucket LDS histogram via segment table -> totals + cand(count>=2) ----
__global__ __launch_bounds__(256) void k_bhist(const uint32_t* __restrict__ bkeys,
                                               const uint32_t* __restrict__ stable,
                                               int nblk,
                                               uint32_t* __restrict__ totals,
                                               uint32_t* __restrict__ cand2,
                                               int* __restrict__ ncand2) {
  __shared__ uint32_t lw[WPB];
  __shared__ uint32_t lt[NCLS];
  __shared__ uint32_t lbuf[DLCAP];
  __shared__ uint32_t lcnt, lbase;
  int b = blockIdx.x;
  for (int w = threadIdx.x; w < WPB; w += 256) lw[w] = 0;
  if (threadIdx.x < NCLS) lt[threadIdx.x] = 0;
  if (threadIdx.x == 0) lcnt = 0;
  __syncthreads();
  uint32_t base = (uint32_t)b * BUCKSZ;
  for (int blk = threadIdx.x; blk < nblk; blk += 256) {
    size_t tb = (size_t)blk * (NB + 1);
    uint32_t s = stable[tb + b], e = stable[tb + b + 1];
    for (uint32_t j = s; j < e; ++j) {
      uint32_t k = bkeys[j];
      if (k < KCELLS) {      // aliased/OOB keys dropped (scatter-add semantics)
        uint32_t off = k - base;
        atomicAdd(&lw[off >> 2], 1u << ((off & 3) * 8));
      }
    }
  }
  __syncthreads();
  for (int w = threadIdx.x; w < WPB; w += 256) {
    uint32_t word = lw[w];
    if (!word) continue;
#pragma unroll
    for (int eb = 0; eb < 4; ++eb) {
      uint32_t v = (word >> (eb * 8)) & 0xFFu;
      if (v) {
        atomicAdd(&lt[min(v, 31u)], 1u);
        if (v >= 2u) {
          uint32_t sv = (min(v, 127u) << 25) | (KEYMASK - (base + (uint32_t)(w * 4 + eb)));
          uint32_t pos = atomicAdd(&lcnt, 1u);
          if (pos < DLCAP) lbuf[pos] = sv;
          else { int gp = atomicAdd(ncand2, 1); if (gp < CAND2CAP) cand2[gp] = sv; }
        }
      }
    }
  }
  __syncthreads();
  uint32_t cnt = min(lcnt, (uint32_t)DLCAP);
  if (threadIdx.x == 0) lbase = (uint32_t)atomicAdd(ncand2, (int)cnt);
  __syncthreads();
  for (uint32_t j = threadIdx.x; j < cnt; j += 256)
    if (lbase + j < CAND2CAP) cand2[lbase + j] = lbuf[j];
  __syncthreads();
  if (threadIdx.x < NCLS && lt[threadIdx.x]) atomicAdd(&totals[threadIdx.x], lt[threadIdx.x]);
}

// ---- K3: threshold T ----
__global__ void k_thr(const uint32_t* __restrict__ totals, int* __restrict__ ctrl) {
  if (threadIdx.x != 0 || blockIdx.x != 0) return;
  int suffix[NCLS];
  suffix[NCLS - 1] = 0;
  for (int c = NCLS - 2; c >= 0; --c) suffix[c] = suffix[c + 1] + (int)totals[c + 1];
  int T = NCLS - 1;
  for (int c = 1; c < NCLS; ++c) { if (suffix[c] <= MAXV) { T = c; break; } }
  ctrl[0] = T;
}

// ---- K4: filter cand2 by count >= T ----
__global__ __launch_bounds__(256) void k_collect2(const uint32_t* __restrict__ cand2,
                                                  const int* __restrict__ nc2_p,
                                                  const int* __restrict__ ctrl,
                                                  uint32_t* __restrict__ cand,
                                                  int* __restrict__ ncand) {
  __shared__ uint32_t lbuf[LCAP];
  __shared__ uint32_t lcnt, lbase;
  if (threadIdx.x == 0) lcnt = 0;
  __syncthreads();
  uint32_t T = (uint32_t)ctrl[0];
  int n2 = min(*nc2_p, CAND2CAP);
  int stride = gridDim.x * blockDim.x;
  for (int i = blockIdx.x * blockDim.x + threadIdx.x; i < n2; i += stride) {
    uint32_t sv = cand2[i];
    if ((sv >> 25) >= T) {
      uint32_t pos = atomicAdd(&lcnt, 1u);
      if (pos < LCAP) lbuf[pos] = sv;
      else { int gp = atomicAdd(ncand, 1); if (gp < CANDCAP) cand[gp] = sv; }
    }
  }
  __syncthreads();
  uint32_t cnt = min(lcnt, (uint32_t)LCAP);
  if (threadIdx.x == 0) lbase = (uint32_t)atomicAdd(ncand, (int)cnt);
  __syncthreads();
  for (uint32_t j = threadIdx.x; j < cnt; j += 256)
    if (lbase + j < CANDCAP) cand[lbase + j] = lbuf[j];
}

// ---- R1: s-bucket histogram ----
__global__ __launch_bounds__(256) void k_bh1(const uint32_t* __restrict__ cand,
                                             const int* __restrict__ ncand_p,
                                             uint32_t* __restrict__ bh) {
  __shared__ uint32_t lh[SB];
  for (int j = threadIdx.x; j < SB; j += 256) lh[j] = 0;
  __syncthreads();
  int n = min(*ncand_p, CANDCAP);
  int stride = gridDim.x * blockDim.x;
  for (int i = blockIdx.x * blockDim.x + threadIdx.x; i < n; i += stride)
    atomicAdd(&lh[min(cand[i] >> 17, (uint32_t)(SB - 1))], 1u);
  __syncthreads();
  for (int j = threadIdx.x; j < SB; j += 256) if (lh[j]) atomicAdd(&bh[j], lh[j]);
}

// ---- R2: suffix-exclusive scan over s-buckets ----
__global__ __launch_bounds__(1024) void k_bscan2(const uint32_t* __restrict__ bh,
                                                 uint32_t* __restrict__ sboff,
                                                 uint32_t* __restrict__ scur) {
  __shared__ uint32_t wsum[16];
  int t = threadIdx.x;
  uint32_t v[4];
  uint32_t s = 0;
#pragma unroll
  for (int e = 0; e < 4; ++e) { v[e] = bh[SB - 1 - (t * 4 + e)]; s += v[e]; }
  uint32_t incl = s;
#pragma unroll
  for (int d = 1; d < 64; d <<= 1) {
    uint32_t up = __shfl_up(incl, d);
    if ((t & 63) >= d) incl += up;
  }
  int wave = t >> 6;
  if ((t & 63) == 63) wsum[wave] = incl;
  __syncthreads();
  if (t == 0) {
    uint32_t run = 0;
    for (int w = 0; w < 16; ++w) { uint32_t tmp = wsum[w]; wsum[w] = run; run += tmp; }
  }
  __syncthreads();
  uint32_t excl = wsum[wave] + incl - s;
#pragma unroll
  for (int e = 0; e < 4; ++e) {
    int b = SB - 1 - (t * 4 + e);
    sboff[b] = excl; scur[b] = 0;
    excl += v[e];
  }
}

// ---- R3: counting-sort placement ----
__global__ void k_place(const uint32_t* __restrict__ cand, const int* __restrict__ ncand_p,
                        const uint32_t* __restrict__ sboff, uint32_t* __restrict__ scur,
                        uint32_t* __restrict__ ss) {
  int n = min(*ncand_p, CANDCAP);
  int i = blockIdx.x * blockDim.x + threadIdx.x;
  if (i >= n) return;
  uint32_t s = cand[i];
  uint32_t b = min(s >> 17, (uint32_t)(SB - 1));
  uint32_t slot = sboff[b] + atomicAdd(&scur[b], 1u);
  ss[slot] = s;
}

// ---- R4: exact rank via segment scan; rank<MAXV -> hash insert + sel arrays ----
__global__ void k_rank2(const uint32_t* __restrict__ ss, const int* __restrict__ ncand_p,
                        const uint32_t* __restrict__ sboff, const uint32_t* __restrict__ bh,
                        unsigned long long* __restrict__ tab,
                        int* __restrict__ sel_key, uint32_t* __restrict__ sel_cnt) {
  int n = min(*ncand_p, CANDCAP);
  int p = blockIdx.x * blockDim.x + threadIdx.x;
  if (p >= n) return;
  uint32_t s = ss[p];
  uint32_t b = min(s >> 17, (uint32_t)(SB - 1));
  uint32_t st = sboff[b], cnt = bh[b];
  int r = (int)st;
  for (uint32_t q = st; q < st + cnt; ++q) r += (ss[q] > s) ? 1 : 0;
  if (r < MAXV) {
    uint32_t key = KEYMASK - (s & KEYMASK);
    sel_key[r] = (int)key;
    sel_cnt[r] = s >> 25;
    unsigned long long pack = ((unsigned long long)(uint32_t)r << 32) | key;
    uint32_t slot = keyhash(key);
    while (true) {
      unsigned long long old = atomicCAS(&tab[slot & TMASK], TEMPTY, pack);
      if (old == TEMPTY) break;
      ++slot;
    }
  }
}

// ---- K6: coords + num outputs ----
__global__ void k_meta(const int* __restrict__ sel_key, const uint32_t* __restrict__ sel_cnt,
                       float* __restrict__ coords_out, float* __restrict__ num_out) {
  int id = blockIdx.x * blockDim.x + threadIdx.x;
  if (id >= MAXV) return;
  int key = sel_key[id];
  if (key < 0) return;
  int ix = key / GYZ;
  int iy = (key / GZ_K) % GY_K;
  int iz = key % GZ_K;
  coords_out[id * 3 + 0] = (float)ix;
  coords_out[id * 3 + 1] = (float)iy;
  coords_out[id * 3 + 2] = (float)iz;
  num_out[id] = (float)min(sel_cnt[id], (uint32_t)MAXP);
}

// ---- K7: scatter via stored keys + hash lookup (gather clamps) ----
__global__ void k_scatter(const uint32_t* __restrict__ keys,
                          const unsigned long long* __restrict__ tab,
                          int* __restrict__ vcnt, int* __restrict__ slots, int N) {
  int i = blockIdx.x * blockDim.x + threadIdx.x;
  if (i >= N) return;
  uint32_t key = keys[i];
  if (key >= KCELLS) key = KCELLS - 1;   // jnp gather clip
  uint32_t slot = keyhash(key);
  int id = -1;
  while (true) {
    unsigned long long v = tab[slot & TMASK];
    if (v == TEMPTY) break;
    if ((uint32_t)v == key) { id = (int)(v >> 32); break; }
    ++slot;
  }
  if (id >= 0) {
    int slotp = atomicAdd(&vcnt[id], 1);
    if (slotp < MAXP) slots[id * MAXP + slotp] = i;
  }
}

// ---- K8: stable per-voxel rank + emit ----
__global__ void k_emit(const float4* __restrict__ pts, const int* __restrict__ vcnt,
                       const int* __restrict__ slots, float4* __restrict__ vox) {
  int vid = blockIdx.x * 8 + (threadIdx.x >> 5);
  int lane = threadIdx.x & 31;
  __shared__ int sidx[256];
  int idx = INT_MAX;
  int n = 0;
  if (vid < MAXV) {
    n = min(vcnt[vid], MAXP);
    if (lane < n) idx = slots[vid * MAXP + lane];
  }
  sidx[threadIdx.x] = idx;
  __syncthreads();
  if (vid < MAXV && lane < n) {
    int rank = 0;
    int gbase = (threadIdx.x >> 5) << 5;
    for (int j = 0; j < 32; ++j) rank += (sidx[gbase + j] < idx) ? 1 : 0;
    vox[vid * MAXP + rank] = pts[idx];
  }
}

extern "C" void kernel_launch(void* const* d_in, const int* in_sizes, int n_in,
                              void* d_out, int out_size, void* d_ws, size_t ws_size,
                              hipStream_t stream) {
  const float4* pts = (const float4*)d_in[0];
  const int N = in_sizes[0] / 4;
  const int nblk = (N + PCHUNK - 1) / PCHUNK;

  float* out = (float*)d_out;
  float* coords_out = out + (size_t)MAXV * MAXP * 4;
  float* num_out = coords_out + (size_t)MAXV * 3;

  uint8_t* wsb = (uint8_t*)d_ws;
  size_t off = 0;
  auto take = [&](size_t bytes) -> uint8_t* {
    uint8_t* p = wsb + off;
    off = (off + bytes + 255) & ~(size_t)255;
    return p;
  };
  uint32_t* keys = (uint32_t*)take((size_t)N * 4);               // 16 MB
  uint32_t* bkeys = (uint32_t*)take((size_t)N * 4);              // 16 MB
  uint32_t* stable = (uint32_t*)take((size_t)nblk * (NB + 1) * 4); // ~1 MB
  uint32_t* totals = (uint32_t*)take(NCLS * 4);
  int* ctrl = (int*)take(64);                                    // [2]=ncand [4]=ncand2
  uint32_t* cand2 = (uint32_t*)take((size_t)CAND2CAP * 4);       // 4 MB
  uint32_t* cand = (uint32_t*)take((size_t)CANDCAP * 4);         // 2 MB
  uint32_t* ss = (uint32_t*)take((size_t)CANDCAP * 4);           // 2 MB
  uint32_t* bh = (uint32_t*)take(SB * 4);
  uint32_t* sboff = (uint32_t*)take(SB * 4);
  uint32_t* scur = (uint32_t*)take(SB * 4);
  unsigned long long* tab = (unsigned long long*)take((size_t)TSIZE * 8);  // 512 KB
  int* sel_key = (int*)take((size_t)MAXV * 4);
  uint32_t* sel_cnt = (uint32_t*)take((size_t)MAXV * 4);
  int* vcnt = (int*)take((size_t)MAXV * 4);
  int* slots = (int*)take((size_t)MAXV * MAXP * 4);              // 2.56 MB
  (void)ws_size;  // ~45 MB total

  hipMemsetAsync(totals, 0, NCLS * 4, stream);
  hipMemsetAsync(ctrl, 0, 64, stream);
  hipMemsetAsync(bh, 0, SB * 4, stream);
  hipMemsetAsync(tab, 0xFF, (size_t)TSIZE * 8, stream);
  hipMemsetAsync(vcnt, 0, (size_t)MAXV * 4, stream);
  hipMemsetAsync(sel_key, 0xFF, (size_t)MAXV * 4, stream);
  hipMemsetAsync(d_out, 0, (size_t)out_size * sizeof(float), stream);

  k_kp<<<nblk, PTH, 0, stream>>>(pts, N, keys, bkeys, stable);
  k_bhist<<<NB, 256, 0, stream>>>(bkeys, stable, nblk, totals, cand2, &ctrl[4]);
  k_thr<<<1, 64, 0, stream>>>(totals, ctrl);
  k_collect2<<<64, 256, 0, stream>>>(cand2, &ctrl[4], ctrl, cand, &ctrl[2]);
  k_bh1<<<32, 256, 0, stream>>>(cand, &ctrl[2], bh);
  k_bscan2<<<1, 1024, 0, stream>>>(bh, sboff, scur);
  k_place<<<CANDCAP / 256, 256, 0, stream>>>(cand, &ctrl[2], sboff, scur, ss);
  k_rank2<<<CANDCAP / 256, 256, 0, stream>>>(ss, &ctrl[2], sboff, bh, tab, sel_key, sel_cnt);
  k_meta<<<(MAXV + 255) / 256, 256, 0, stream>>>(sel_key, sel_cnt, coords_out, num_out);
  k_scatter<<<(N + 255) / 256, 256, 0, stream>>>(keys, tab, vcnt, slots, N);
  k_emit<<<(MAXV + 7) / 8, 256, 0, stream>>>(pts, vcnt, slots, (float4*)out);
}

// Round 26
// 181.757 us; speedup vs baseline: 1.1260x; 1.1260x over previous
//
#include <hip/hip_runtime.h>
#include <stdint.h>
#include <limits.h>

// VERIFIED SEMANTICS (r16, absmax=0):
//  - GRID from module-level numpy f32 floor-divide: (704, 799, 39)
//  - keys: f32 sub, * 10.0f (XLA reciprocal of 0.1f), floorf, cast
//  - scatter-add drops OOB keys; gather clamps; tie-break = key ascending
#define GYZ 31161          // 799*39
#define GY_K 799
#define GZ_K 39
#define KCELLS 21937344    // 704 * 799 * 39
#define MAXV 20000
#define MAXP 32

#define NCLS 32
#define CANDCAP 524288
#define CAND2CAP 1048576
#define KEYMASK 0x1FFFFFFu // 2^25-1; KCELLS < 2^25
#define LCAP 4096
#define TSIZE 65536        // hash table slots (u64), load 0.3
#define TMASK 65535
#define TEMPTY 0xFFFFFFFFFFFFFFFFull

#define NB 1024            // partition buckets (cell-space)
#define BUCKSZ 21424       // cells/bucket; NB*BUCKSZ >= KCELLS
#define WPB (BUCKSZ / 4)   // 5356 LDS words (21.4 KB)
#define PCHUNK 8192        // points per partition block
#define PTH 512
#define PPT (PCHUNK / PTH) // 16 keys per thread
#define DLCAP 1024         // k_bhist per-block cand buffer
#define NSEG 512           // segment-table tile in k_bhist (nblk=489 fits)

#define SB 4096            // s-value ranking buckets (s >> 17)

__device__ __forceinline__ int point_key(float x, float y, float z) {
  int ix = (int)floorf((x - 0.0f) * 10.0f);
  int iy = (int)floorf((y + 40.0f) * 10.0f);
  int iz = (int)floorf((z + 3.0f) * 10.0f);
  return (ix * GY_K + iy) * GZ_K + iz;
}

__device__ __forceinline__ uint32_t keyhash(uint32_t key) {
  return (key * 2654435761u) >> 16;
}

// ---- A: fused keys + block-contiguous partition ----
__global__ __launch_bounds__(512) void k_kp(const float4* __restrict__ pts, int N,
                                            uint32_t* __restrict__ keys,
                                            uint32_t* __restrict__ bkeys,
                                            uint32_t* __restrict__ stable) {
  __shared__ uint32_t sk[PCHUNK];       // 32 KB staging
  __shared__ uint32_t lh[NB], lb[NB], cur[NB];
  __shared__ uint32_t wsum[8];
  int blk = blockIdx.x;
  int c0 = blk * PCHUNK;
  int m = min(PCHUNK, N - c0);
  if (m <= 0) return;
  for (int j = threadIdx.x; j < NB; j += PTH) lh[j] = 0;
  __syncthreads();
  uint32_t kreg[PPT];
#pragma unroll
  for (int j = 0; j < PPT; ++j) {
    int idx = j * PTH + threadIdx.x;    // coalesced
    if (idx < m) {
      float4 p = pts[c0 + idx];
      uint32_t key = (uint32_t)point_key(p.x, p.y, p.z);
      kreg[j] = key;
      keys[c0 + idx] = key;
      atomicAdd(&lh[min(key / BUCKSZ, (uint32_t)(NB - 1))], 1u);
    } else kreg[j] = 0xFFFFFFFFu;
  }
  __syncthreads();
  // exclusive scan over 1024 buckets (2 per thread)
  int t = threadIdx.x;
  uint32_t v0 = lh[2 * t], v1 = lh[2 * t + 1];
  uint32_t s = v0 + v1;
  uint32_t incl = s;
#pragma unroll
  for (int d = 1; d < 64; d <<= 1) {
    uint32_t up = __shfl_up(incl, d);
    if ((t & 63) >= d) incl += up;
  }
  int wave = t >> 6;
  if ((t & 63) == 63) wsum[wave] = incl;
  __syncthreads();
  if (t == 0) {
    uint32_t run = 0;
    for (int w = 0; w < 8; ++w) { uint32_t tmp = wsum[w]; wsum[w] = run; run += tmp; }
  }
  __syncthreads();
  uint32_t excl = wsum[wave] + incl - s;
  lb[2 * t] = excl;          lb[2 * t + 1] = excl + v0;
  cur[2 * t] = excl;         cur[2 * t + 1] = excl + v0;
  size_t tb = (size_t)blk * (NB + 1);
  stable[tb + 2 * t] = (uint32_t)c0 + excl;
  stable[tb + 2 * t + 1] = (uint32_t)c0 + excl + v0;
  if (t == 0) stable[tb + NB] = (uint32_t)(c0 + m);
  __syncthreads();
#pragma unroll
  for (int j = 0; j < PPT; ++j) {
    uint32_t key = kreg[j];
    if (key != 0xFFFFFFFFu) {
      uint32_t b = min(key / BUCKSZ, (uint32_t)(NB - 1));
      sk[atomicAdd(&cur[b], 1u)] = key;
    }
  }
  __syncthreads();
  for (int j = threadIdx.x; j < m; j += PTH) bkeys[c0 + j] = sk[j];  // contiguous
}

// ---- D: per-bucket LDS histogram, flattened cooperative gather ----
__global__ __launch_bounds__(512) void k_bhist(const uint32_t* __restrict__ bkeys,
                                               const uint32_t* __restrict__ stable,
                                               int nblk,
                                               uint32_t* __restrict__ totals,
                                               uint32_t* __restrict__ cand2,
                                               int* __restrict__ ncand2) {
  __shared__ uint32_t lw[WPB];
  __shared__ uint32_t lt[NCLS];
  __shared__ uint32_t lbuf[DLCAP];
  __shared__ uint32_t lcnt, lbase;
  __shared__ uint32_t segs[NSEG];       // segment start (abs index into bkeys)
  __shared__ uint32_t pfx[NSEG + 1];    // exclusive prefix of segment lengths
  __shared__ uint32_t wsum[8];
  int b = blockIdx.x;
  int t = threadIdx.x;
  for (int w = t; w < WPB; w += 512) lw[w] = 0;
  if (t < NCLS) lt[t] = 0;
  if (t == 0) lcnt = 0;
  __syncthreads();
  uint32_t base = (uint32_t)b * BUCKSZ;
  for (int s0 = 0; s0 < nblk; s0 += NSEG) {
    int nseg = min(NSEG, nblk - s0);
    uint32_t len = 0;
    if (t < nseg) {
      size_t tb = (size_t)(s0 + t) * (NB + 1);
      uint32_t s = stable[tb + b];
      uint32_t e = stable[tb + b + 1];
      segs[t] = s;
      len = e - s;
    }
    // 512-thread exclusive scan of len
    uint32_t incl = len;
#pragma unroll
    for (int d = 1; d < 64; d <<= 1) {
      uint32_t up = __shfl_up(incl, d);
      if ((t & 63) >= d) incl += up;
    }
    int wave = t >> 6;
    if ((t & 63) == 63) wsum[wave] = incl;
    __syncthreads();
    if (t == 0) {
      uint32_t run = 0;
      for (int w = 0; w < 8; ++w) { uint32_t tmp = wsum[w]; wsum[w] = run; run += tmp; }
    }
    __syncthreads();
    uint32_t excl = wsum[wave] + incl - len;
    if (t < nseg) pfx[t] = excl;
    if (t == nseg - 1 || (t == 511 && nseg == 512)) pfx[nseg] = excl + len;
    __syncthreads();
    uint32_t L = pfx[nseg];
    for (uint32_t idx = t; idx < L; idx += 512) {
      int lo = 0, hi = nseg;          // largest c with pfx[c] <= idx
      while (hi - lo > 1) { int mid = (lo + hi) >> 1; if (pfx[mid] <= idx) lo = mid; else hi = mid; }
      uint32_t k = bkeys[segs[lo] + (idx - pfx[lo])];
      if (k < KCELLS) {               // aliased/OOB keys dropped
        uint32_t off = k - base;
        atomicAdd(&lw[off >> 2], 1u << ((off & 3) * 8));
      }
    }
    __syncthreads();
  }
  for (int w = t; w < WPB; w += 512) {
    uint32_t word = lw[w];
    if (!word) continue;
#pragma unroll
    for (int eb = 0; eb < 4; ++eb) {
      uint32_t v = (word >> (eb * 8)) & 0xFFu;
      if (v) {
        atomicAdd(&lt[min(v, 31u)], 1u);
        if (v >= 2u) {
          uint32_t sv = (min(v, 127u) << 25) | (KEYMASK - (base + (uint32_t)(w * 4 + eb)));
          uint32_t pos = atomicAdd(&lcnt, 1u);
          if (pos < DLCAP) lbuf[pos] = sv;
          else { int gp = atomicAdd(ncand2, 1); if (gp < CAND2CAP) cand2[gp] = sv; }
        }
      }
    }
  }
  __syncthreads();
  uint32_t cnt = min(lcnt, (uint32_t)DLCAP);
  if (t == 0) lbase = (uint32_t)atomicAdd(ncand2, (int)cnt);
  __syncthreads();
  for (uint32_t j = t; j < cnt; j += 512)
    if (lbase + j < CAND2CAP) cand2[lbase + j] = lbuf[j];
  __syncthreads();
  if (t < NCLS && lt[t]) atomicAdd(&totals[t], lt[t]);
}

// ---- K3: threshold T ----
__global__ void k_thr(const uint32_t* __restrict__ totals, int* __restrict__ ctrl) {
  if (threadIdx.x != 0 || blockIdx.x != 0) return;
  int suffix[NCLS];
  suffix[NCLS - 1] = 0;
  for (int c = NCLS - 2; c >= 0; --c) suffix[c] = suffix[c + 1] + (int)totals[c + 1];
  int T = NCLS - 1;
  for (int c = 1; c < NCLS; ++c) { if (suffix[c] <= MAXV) { T = c; break; } }
  ctrl[0] = T;
}

// ---- K4: filter cand2 by count >= T ----
__global__ __launch_bounds__(256) void k_collect2(const uint32_t* __restrict__ cand2,
                                                  const int* __restrict__ nc2_p,
                                                  const int* __restrict__ ctrl,
                                                  uint32_t* __restrict__ cand,
                                                  int* __restrict__ ncand) {
  __shared__ uint32_t lbuf[LCAP];
  __shared__ uint32_t lcnt, lbase;
  if (threadIdx.x == 0) lcnt = 0;
  __syncthreads();
  uint32_t T = (uint32_t)ctrl[0];
  int n2 = min(*nc2_p, CAND2CAP);
  int stride = gridDim.x * blockDim.x;
  for (int i = blockIdx.x * blockDim.x + threadIdx.x; i < n2; i += stride) {
    uint32_t sv = cand2[i];
    if ((sv >> 25) >= T) {
      uint32_t pos = atomicAdd(&lcnt, 1u);
      if (pos < LCAP) lbuf[pos] = sv;
      else { int gp = atomicAdd(ncand, 1); if (gp < CANDCAP) cand[gp] = sv; }
    }
  }
  __syncthreads();
  uint32_t cnt = min(lcnt, (uint32_t)LCAP);
  if (threadIdx.x == 0) lbase = (uint32_t)atomicAdd(ncand, (int)cnt);
  __syncthreads();
  for (uint32_t j = threadIdx.x; j < cnt; j += 256)
    if (lbase + j < CANDCAP) cand[lbase + j] = lbuf[j];
}

// ---- R1: s-bucket histogram ----
__global__ __launch_bounds__(256) void k_bh1(const uint32_t* __restrict__ cand,
                                             const int* __restrict__ ncand_p,
                                             uint32_t* __restrict__ bh) {
  __shared__ uint32_t lh[SB];
  for (int j = threadIdx.x; j < SB; j += 256) lh[j] = 0;
  __syncthreads();
  int n = min(*ncand_p, CANDCAP);
  int stride = gridDim.x * blockDim.x;
  for (int i = blockIdx.x * blockDim.x + threadIdx.x; i < n; i += stride)
    atomicAdd(&lh[min(cand[i] >> 17, (uint32_t)(SB - 1))], 1u);
  __syncthreads();
  for (int j = threadIdx.x; j < SB; j += 256) if (lh[j]) atomicAdd(&bh[j], lh[j]);
}

// ---- R2: suffix-exclusive scan over s-buckets ----
__global__ __launch_bounds__(1024) void k_bscan2(const uint32_t* __restrict__ bh,
                                                 uint32_t* __restrict__ sboff,
                                                 uint32_t* __restrict__ scur) {
  __shared__ uint32_t wsum[16];
  int t = threadIdx.x;
  uint32_t v[4];
  uint32_t s = 0;
#pragma unroll
  for (int e = 0; e < 4; ++e) { v[e] = bh[SB - 1 - (t * 4 + e)]; s += v[e]; }
  uint32_t incl = s;
#pragma unroll
  for (int d = 1; d < 64; d <<= 1) {
    uint32_t up = __shfl_up(incl, d);
    if ((t & 63) >= d) incl += up;
  }
  int wave = t >> 6;
  if ((t & 63) == 63) wsum[wave] = incl;
  __syncthreads();
  if (t == 0) {
    uint32_t run = 0;
    for (int w = 0; w < 16; ++w) { uint32_t tmp = wsum[w]; wsum[w] = run; run += tmp; }
  }
  __syncthreads();
  uint32_t excl = wsum[wave] + incl - s;
#pragma unroll
  for (int e = 0; e < 4; ++e) {
    int b = SB - 1 - (t * 4 + e);
    sboff[b] = excl; scur[b] = 0;
    excl += v[e];
  }
}

// ---- R3: counting-sort placement ----
__global__ void k_place(const uint32_t* __restrict__ cand, const int* __restrict__ ncand_p,
                        const uint32_t* __restrict__ sboff, uint32_t* __restrict__ scur,
                        uint32_t* __restrict__ ss) {
  int n = min(*ncand_p, CANDCAP);
  int i = blockIdx.x * blockDim.x + threadIdx.x;
  if (i >= n) return;
  uint32_t s = cand[i];
  uint32_t b = min(s >> 17, (uint32_t)(SB - 1));
  uint32_t slot = sboff[b] + atomicAdd(&scur[b], 1u);
  ss[slot] = s;
}

// ---- R4: exact rank via segment scan; rank<MAXV -> hash insert + sel arrays ----
__global__ void k_rank2(const uint32_t* __restrict__ ss, const int* __restrict__ ncand_p,
                        const uint32_t* __restrict__ sboff, const uint32_t* __restrict__ bh,
                        unsigned long long* __restrict__ tab,
                        int* __restrict__ sel_key, uint32_t* __restrict__ sel_cnt) {
  int n = min(*ncand_p, CANDCAP);
  int p = blockIdx.x * blockDim.x + threadIdx.x;
  if (p >= n) return;
  uint32_t s = ss[p];
  uint32_t b = min(s >> 17, (uint32_t)(SB - 1));
  uint32_t st = sboff[b], cnt = bh[b];
  int r = (int)st;
  for (uint32_t q = st; q < st + cnt; ++q) r += (ss[q] > s) ? 1 : 0;
  if (r < MAXV) {
    uint32_t key = KEYMASK - (s & KEYMASK);
    sel_key[r] = (int)key;
    sel_cnt[r] = s >> 25;
    unsigned long long pack = ((unsigned long long)(uint32_t)r << 32) | key;
    uint32_t slot = keyhash(key);
    while (true) {
      unsigned long long old = atomicCAS(&tab[slot & TMASK], TEMPTY, pack);
      if (old == TEMPTY) break;
      ++slot;
    }
  }
}

// ---- K6: coords + num outputs ----
__global__ void k_meta(const int* __restrict__ sel_key, const uint32_t* __restrict__ sel_cnt,
                       float* __restrict__ coords_out, float* __restrict__ num_out) {
  int id = blockIdx.x * blockDim.x + threadIdx.x;
  if (id >= MAXV) return;
  int key = sel_key[id];
  if (key < 0) return;
  int ix = key / GYZ;
  int iy = (key / GZ_K) % GY_K;
  int iz = key % GZ_K;
  coords_out[id * 3 + 0] = (float)ix;
  coords_out[id * 3 + 1] = (float)iy;
  coords_out[id * 3 + 2] = (float)iz;
  num_out[id] = (float)min(sel_cnt[id], (uint32_t)MAXP);
}

// ---- K7: scatter via stored keys + hash lookup (gather clamps) ----
__global__ void k_scatter(const uint32_t* __restrict__ keys,
                          const unsigned long long* __restrict__ tab,
                          int* __restrict__ vcnt, int* __restrict__ slots, int N) {
  int i = blockIdx.x * blockDim.x + threadIdx.x;
  if (i >= N) return;
  uint32_t key = keys[i];
  if (key >= KCELLS) key = KCELLS - 1;   // jnp gather clip
  uint32_t slot = keyhash(key);
  int id = -1;
  while (true) {
    unsigned long long v = tab[slot & TMASK];
    if (v == TEMPTY) break;
    if ((uint32_t)v == key) { id = (int)(v >> 32); break; }
    ++slot;
  }
  if (id >= 0) {
    int slotp = atomicAdd(&vcnt[id], 1);
    if (slotp < MAXP) slots[id * MAXP + slotp] = i;
  }
}

// ---- K8: stable per-voxel rank + emit ----
__global__ void k_emit(const float4* __restrict__ pts, const int* __restrict__ vcnt,
                       const int* __restrict__ slots, float4* __restrict__ vox) {
  int vid = blockIdx.x * 8 + (threadIdx.x >> 5);
  int lane = threadIdx.x & 31;
  __shared__ int sidx[256];
  int idx = INT_MAX;
  int n = 0;
  if (vid < MAXV) {
    n = min(vcnt[vid], MAXP);
    if (lane < n) idx = slots[vid * MAXP + lane];
  }
  sidx[threadIdx.x] = idx;
  __syncthreads();
  if (vid < MAXV && lane < n) {
    int rank = 0;
    int gbase = (threadIdx.x >> 5) << 5;
    for (int j = 0; j < 32; ++j) rank += (sidx[gbase + j] < idx) ? 1 : 0;
    vox[vid * MAXP + rank] = pts[idx];
  }
}

extern "C" void kernel_launch(void* const* d_in, const int* in_sizes, int n_in,
                              void* d_out, int out_size, void* d_ws, size_t ws_size,
                              hipStream_t stream) {
  const float4* pts = (const float4*)d_in[0];
  const int N = in_sizes[0] / 4;
  const int nblk = (N + PCHUNK - 1) / PCHUNK;

  float* out = (float*)d_out;
  float* coords_out = out + (size_t)MAXV * MAXP * 4;
  float* num_out = coords_out + (size_t)MAXV * 3;

  uint8_t* wsb = (uint8_t*)d_ws;
  size_t off = 0;
  auto take = [&](size_t bytes) -> uint8_t* {
    uint8_t* p = wsb + off;
    off = (off + bytes + 255) & ~(size_t)255;
    return p;
  };
  uint32_t* keys = (uint32_t*)take((size_t)N * 4);               // 16 MB
  uint32_t* bkeys = (uint32_t*)take((size_t)N * 4);              // 16 MB
  uint32_t* stable = (uint32_t*)take((size_t)nblk * (NB + 1) * 4); // ~2 MB
  uint32_t* totals = (uint32_t*)take(NCLS * 4);
  int* ctrl = (int*)take(64);                                    // [2]=ncand [4]=ncand2
  uint32_t* cand2 = (uint32_t*)take((size_t)CAND2CAP * 4);       // 4 MB
  uint32_t* cand = (uint32_t*)take((size_t)CANDCAP * 4);         // 2 MB
  uint32_t* ss = (uint32_t*)take((size_t)CANDCAP * 4);           // 2 MB
  uint32_t* bh = (uint32_t*)take(SB * 4);
  uint32_t* sboff = (uint32_t*)take(SB * 4);
  uint32_t* scur = (uint32_t*)take(SB * 4);
  unsigned long long* tab = (unsigned long long*)take((size_t)TSIZE * 8);  // 512 KB
  int* sel_key = (int*)take((size_t)MAXV * 4);
  uint32_t* sel_cnt = (uint32_t*)take((size_t)MAXV * 4);
  int* vcnt = (int*)take((size_t)MAXV * 4);
  int* slots = (int*)take((size_t)MAXV * MAXP * 4);              // 2.56 MB
  (void)ws_size;  // ~46 MB total

  hipMemsetAsync(totals, 0, NCLS * 4, stream);
  hipMemsetAsync(ctrl, 0, 64, stream);
  hipMemsetAsync(bh, 0, SB * 4, stream);
  hipMemsetAsync(tab, 0xFF, (size_t)TSIZE * 8, stream);
  hipMemsetAsync(vcnt, 0, (size_t)MAXV * 4, stream);
  hipMemsetAsync(sel_key, 0xFF, (size_t)MAXV * 4, stream);
  hipMemsetAsync(d_out, 0, (size_t)out_size * sizeof(float), stream);

  k_kp<<<nblk, PTH, 0, stream>>>(pts, N, keys, bkeys, stable);
  k_bhist<<<NB, 512, 0, stream>>>(bkeys, stable, nblk, totals, cand2, &ctrl[4]);
  k_thr<<<1, 64, 0, stream>>>(totals, ctrl);
  k_collect2<<<64, 256, 0, stream>>>(cand2, &ctrl[4], ctrl, cand, &ctrl[2]);
  k_bh1<<<32, 256, 0, stream>>>(cand, &ctrl[2], bh);
  k_bscan2<<<1, 1024, 0, stream>>>(bh, sboff, scur);
  k_place<<<CANDCAP / 256, 256, 0, stream>>>(cand, &ctrl[2], sboff, scur, ss);
  k_rank2<<<CANDCAP / 256, 256, 0, stream>>>(ss, &ctrl[2], sboff, bh, tab, sel_key, sel_cnt);
  k_meta<<<(MAXV + 255) / 256, 256, 0, stream>>>(sel_key, sel_cnt, coords_out, num_out);
  k_scatter<<<(N + 255) / 256, 256, 0, stream>>>(keys, tab, vcnt, slots, N);
  k_emit<<<(MAXV + 7) / 8, 256, 0, stream>>>(pts, vcnt, slots, (float4*)out);
}

// Round 27
// 177.764 us; speedup vs baseline: 1.1513x; 1.0225x over previous
//
#include <hip/hip_runtime.h>
#include <stdint.h>
#include <limits.h>

// VERIFIED SEMANTICS (r16, absmax=0):
//  - GRID from module-level numpy f32 floor-divide: (704, 799, 39)
//  - keys: f32 sub, * 10.0f (XLA reciprocal of 0.1f), floorf, cast
//  - scatter-add drops OOB keys; gather clamps; tie-break = key ascending
#define GYZ 31161          // 799*39
#define GY_K 799
#define GZ_K 39
#define KCELLS 21937344    // 704 * 799 * 39
#define MAXV 20000
#define MAXP 32

#define NCLS 32
#define CANDCAP 524288
#define CAND2CAP 1048576
#define KEYMASK 0x1FFFFFFu // 2^25-1; KCELLS < 2^25
#define LCAP 4096
#define TSIZE 65536        // hash table slots (u64), load 0.3
#define TMASK 65535
#define TEMPTY 0xFFFFFFFFFFFFFFFFull
#define BMWORDS ((KCELLS + 31) / 32)   // selection bitmap words (2.74 MB)

#define NB 1024            // partition buckets (cell-space)
#define BUCKSZ 21424       // cells/bucket; NB*BUCKSZ >= KCELLS
#define WPB (BUCKSZ / 4)   // 5356 LDS words (21.4 KB)
#define PCHUNK 8192        // points per partition block
#define PTH 512
#define PPT (PCHUNK / PTH) // 16 keys per thread
#define DLCAP 1024         // k_bhist per-block cand buffer
#define NSEG 512           // segment-table tile in k_bhist (nblk=489 fits)

#define SB 4096            // s-value ranking buckets (s >> 17)

__device__ __forceinline__ int point_key(float x, float y, float z) {
  int ix = (int)floorf((x - 0.0f) * 10.0f);
  int iy = (int)floorf((y + 40.0f) * 10.0f);
  int iz = (int)floorf((z + 3.0f) * 10.0f);
  return (ix * GY_K + iy) * GZ_K + iz;
}

__device__ __forceinline__ uint32_t keyhash(uint32_t key) {
  return (key * 2654435761u) >> 16;
}

// ---- A: fused keys + block-contiguous partition ----
__global__ __launch_bounds__(512) void k_kp(const float4* __restrict__ pts, int N,
                                            uint32_t* __restrict__ keys,
                                            uint32_t* __restrict__ bkeys,
                                            uint32_t* __restrict__ stable) {
  __shared__ uint32_t sk[PCHUNK];       // 32 KB staging
  __shared__ uint32_t lh[NB], lb[NB], cur[NB];
  __shared__ uint32_t wsum[8];
  int blk = blockIdx.x;
  int c0 = blk * PCHUNK;
  int m = min(PCHUNK, N - c0);
  if (m <= 0) return;
  for (int j = threadIdx.x; j < NB; j += PTH) lh[j] = 0;
  __syncthreads();
  uint32_t kreg[PPT];
#pragma unroll
  for (int j = 0; j < PPT; ++j) {
    int idx = j * PTH + threadIdx.x;    // coalesced
    if (idx < m) {
      float4 p = pts[c0 + idx];
      uint32_t key = (uint32_t)point_key(p.x, p.y, p.z);
      kreg[j] = key;
      keys[c0 + idx] = key;
      atomicAdd(&lh[min(key / BUCKSZ, (uint32_t)(NB - 1))], 1u);
    } else kreg[j] = 0xFFFFFFFFu;
  }
  __syncthreads();
  // exclusive scan over 1024 buckets (2 per thread)
  int t = threadIdx.x;
  uint32_t v0 = lh[2 * t], v1 = lh[2 * t + 1];
  uint32_t s = v0 + v1;
  uint32_t incl = s;
#pragma unroll
  for (int d = 1; d < 64; d <<= 1) {
    uint32_t up = __shfl_up(incl, d);
    if ((t & 63) >= d) incl += up;
  }
  int wave = t >> 6;
  if ((t & 63) == 63) wsum[wave] = incl;
  __syncthreads();
  if (t == 0) {
    uint32_t run = 0;
    for (int w = 0; w < 8; ++w) { uint32_t tmp = wsum[w]; wsum[w] = run; run += tmp; }
  }
  __syncthreads();
  uint32_t excl = wsum[wave] + incl - s;
  lb[2 * t] = excl;          lb[2 * t + 1] = excl + v0;
  cur[2 * t] = excl;         cur[2 * t + 1] = excl + v0;
  size_t tb = (size_t)blk * (NB + 1);
  stable[tb + 2 * t] = (uint32_t)c0 + excl;
  stable[tb + 2 * t + 1] = (uint32_t)c0 + excl + v0;
  if (t == 0) stable[tb + NB] = (uint32_t)(c0 + m);
  __syncthreads();
#pragma unroll
  for (int j = 0; j < PPT; ++j) {
    uint32_t key = kreg[j];
    if (key != 0xFFFFFFFFu) {
      uint32_t b = min(key / BUCKSZ, (uint32_t)(NB - 1));
      sk[atomicAdd(&cur[b], 1u)] = key;
    }
  }
  __syncthreads();
  for (int j = threadIdx.x; j < m; j += PTH) bkeys[c0 + j] = sk[j];  // contiguous
}

// ---- D: per-bucket LDS histogram, flattened cooperative gather ----
__global__ __launch_bounds__(512) void k_bhist(const uint32_t* __restrict__ bkeys,
                                               const uint32_t* __restrict__ stable,
                                               int nblk,
                                               uint32_t* __restrict__ totals,
                                               uint32_t* __restrict__ cand2,
                                               int* __restrict__ ncand2) {
  __shared__ uint32_t lw[WPB];
  __shared__ uint32_t lt[NCLS];
  __shared__ uint32_t lbuf[DLCAP];
  __shared__ uint32_t lcnt, lbase;
  __shared__ uint32_t segs[NSEG];
  __shared__ uint32_t pfx[NSEG + 1];
  __shared__ uint32_t wsum[8];
  int b = blockIdx.x;
  int t = threadIdx.x;
  for (int w = t; w < WPB; w += 512) lw[w] = 0;
  if (t < NCLS) lt[t] = 0;
  if (t == 0) lcnt = 0;
  __syncthreads();
  uint32_t base = (uint32_t)b * BUCKSZ;
  for (int s0 = 0; s0 < nblk; s0 += NSEG) {
    int nseg = min(NSEG, nblk - s0);
    uint32_t len = 0;
    if (t < nseg) {
      size_t tb = (size_t)(s0 + t) * (NB + 1);
      uint32_t s = stable[tb + b];
      uint32_t e = stable[tb + b + 1];
      segs[t] = s;
      len = e - s;
    }
    uint32_t incl = len;
#pragma unroll
    for (int d = 1; d < 64; d <<= 1) {
      uint32_t up = __shfl_up(incl, d);
      if ((t & 63) >= d) incl += up;
    }
    int wave = t >> 6;
    if ((t & 63) == 63) wsum[wave] = incl;
    __syncthreads();
    if (t == 0) {
      uint32_t run = 0;
      for (int w = 0; w < 8; ++w) { uint32_t tmp = wsum[w]; wsum[w] = run; run += tmp; }
    }
    __syncthreads();
    uint32_t excl = wsum[wave] + incl - len;
    if (t < nseg) pfx[t] = excl;
    if (t == nseg - 1 || (t == 511 && nseg == 512)) pfx[nseg] = excl + len;
    __syncthreads();
    uint32_t L = pfx[nseg];
    for (uint32_t idx = t; idx < L; idx += 512) {
      int lo = 0, hi = nseg;
      while (hi - lo > 1) { int mid = (lo + hi) >> 1; if (pfx[mid] <= idx) lo = mid; else hi = mid; }
      uint32_t k = bkeys[segs[lo] + (idx - pfx[lo])];
      if (k < KCELLS) {
        uint32_t off = k - base;
        atomicAdd(&lw[off >> 2], 1u << ((off & 3) * 8));
      }
    }
    __syncthreads();
  }
  for (int w = t; w < WPB; w += 512) {
    uint32_t word = lw[w];
    if (!word) continue;
#pragma unroll
    for (int eb = 0; eb < 4; ++eb) {
      uint32_t v = (word >> (eb * 8)) & 0xFFu;
      if (v) {
        atomicAdd(&lt[min(v, 31u)], 1u);
        if (v >= 2u) {
          uint32_t sv = (min(v, 127u) << 25) | (KEYMASK - (base + (uint32_t)(w * 4 + eb)));
          uint32_t pos = atomicAdd(&lcnt, 1u);
          if (pos < DLCAP) lbuf[pos] = sv;
          else { int gp = atomicAdd(ncand2, 1); if (gp < CAND2CAP) cand2[gp] = sv; }
        }
      }
    }
  }
  __syncthreads();
  uint32_t cnt = min(lcnt, (uint32_t)DLCAP);
  if (t == 0) lbase = (uint32_t)atomicAdd(ncand2, (int)cnt);
  __syncthreads();
  for (uint32_t j = t; j < cnt; j += 512)
    if (lbase + j < CAND2CAP) cand2[lbase + j] = lbuf[j];
  __syncthreads();
  if (t < NCLS && lt[t]) atomicAdd(&totals[t], lt[t]);
}

// ---- K3: threshold T ----
__global__ void k_thr(const uint32_t* __restrict__ totals, int* __restrict__ ctrl) {
  if (threadIdx.x != 0 || blockIdx.x != 0) return;
  int suffix[NCLS];
  suffix[NCLS - 1] = 0;
  for (int c = NCLS - 2; c >= 0; --c) suffix[c] = suffix[c + 1] + (int)totals[c + 1];
  int T = NCLS - 1;
  for (int c = 1; c < NCLS; ++c) { if (suffix[c] <= MAXV) { T = c; break; } }
  ctrl[0] = T;
}

// ---- K4: filter cand2 by count >= T ----
__global__ __launch_bounds__(256) void k_collect2(const uint32_t* __restrict__ cand2,
                                                  const int* __restrict__ nc2_p,
                                                  const int* __restrict__ ctrl,
                                                  uint32_t* __restrict__ cand,
                                                  int* __restrict__ ncand) {
  __shared__ uint32_t lbuf[LCAP];
  __shared__ uint32_t lcnt, lbase;
  if (threadIdx.x == 0) lcnt = 0;
  __syncthreads();
  uint32_t T = (uint32_t)ctrl[0];
  int n2 = min(*nc2_p, CAND2CAP);
  int stride = gridDim.x * blockDim.x;
  for (int i = blockIdx.x * blockDim.x + threadIdx.x; i < n2; i += stride) {
    uint32_t sv = cand2[i];
    if ((sv >> 25) >= T) {
      uint32_t pos = atomicAdd(&lcnt, 1u);
      if (pos < LCAP) lbuf[pos] = sv;
      else { int gp = atomicAdd(ncand, 1); if (gp < CANDCAP) cand[gp] = sv; }
    }
  }
  __syncthreads();
  uint32_t cnt = min(lcnt, (uint32_t)LCAP);
  if (threadIdx.x == 0) lbase = (uint32_t)atomicAdd(ncand, (int)cnt);
  __syncthreads();
  for (uint32_t j = threadIdx.x; j < cnt; j += 256)
    if (lbase + j < CANDCAP) cand[lbase + j] = lbuf[j];
}

// ---- R1: s-bucket histogram ----
__global__ __launch_bounds__(256) void k_bh1(const uint32_t* __restrict__ cand,
                                             const int* __restrict__ ncand_p,
                                             uint32_t* __restrict__ bh) {
  __shared__ uint32_t lh[SB];
  for (int j = threadIdx.x; j < SB; j += 256) lh[j] = 0;
  __syncthreads();
  int n = min(*ncand_p, CANDCAP);
  int stride = gridDim.x * blockDim.x;
  for (int i = blockIdx.x * blockDim.x + threadIdx.x; i < n; i += stride)
    atomicAdd(&lh[min(cand[i] >> 17, (uint32_t)(SB - 1))], 1u);
  __syncthreads();
  for (int j = threadIdx.x; j < SB; j += 256) if (lh[j]) atomicAdd(&bh[j], lh[j]);
}

// ---- R2: suffix-exclusive scan over s-buckets ----
__global__ __launch_bounds__(1024) void k_bscan2(const uint32_t* __restrict__ bh,
                                                 uint32_t* __restrict__ sboff,
                                                 uint32_t* __restrict__ scur) {
  __shared__ uint32_t wsum[16];
  int t = threadIdx.x;
  uint32_t v[4];
  uint32_t s = 0;
#pragma unroll
  for (int e = 0; e < 4; ++e) { v[e] = bh[SB - 1 - (t * 4 + e)]; s += v[e]; }
  uint32_t incl = s;
#pragma unroll
  for (int d = 1; d < 64; d <<= 1) {
    uint32_t up = __shfl_up(incl, d);
    if ((t & 63) >= d) incl += up;
  }
  int wave = t >> 6;
  if ((t & 63) == 63) wsum[wave] = incl;
  __syncthreads();
  if (t == 0) {
    uint32_t run = 0;
    for (int w = 0; w < 16; ++w) { uint32_t tmp = wsum[w]; wsum[w] = run; run += tmp; }
  }
  __syncthreads();
  uint32_t excl = wsum[wave] + incl - s;
#pragma unroll
  for (int e = 0; e < 4; ++e) {
    int b = SB - 1 - (t * 4 + e);
    sboff[b] = excl; scur[b] = 0;
    excl += v[e];
  }
}

// ---- R3: counting-sort placement ----
__global__ void k_place(const uint32_t* __restrict__ cand, const int* __restrict__ ncand_p,
                        const uint32_t* __restrict__ sboff, uint32_t* __restrict__ scur,
                        uint32_t* __restrict__ ss) {
  int n = min(*ncand_p, CANDCAP);
  int i = blockIdx.x * blockDim.x + threadIdx.x;
  if (i >= n) return;
  uint32_t s = cand[i];
  uint32_t b = min(s >> 17, (uint32_t)(SB - 1));
  uint32_t slot = sboff[b] + atomicAdd(&scur[b], 1u);
  ss[slot] = s;
}

// ---- R4: exact rank; rank<MAXV -> hash insert + bitmap + sel arrays ----
__global__ void k_rank2(const uint32_t* __restrict__ ss, const int* __restrict__ ncand_p,
                        const uint32_t* __restrict__ sboff, const uint32_t* __restrict__ bh,
                        unsigned long long* __restrict__ tab,
                        uint32_t* __restrict__ selbm,
                        int* __restrict__ sel_key, uint32_t* __restrict__ sel_cnt) {
  int n = min(*ncand_p, CANDCAP);
  int p = blockIdx.x * blockDim.x + threadIdx.x;
  if (p >= n) return;
  uint32_t s = ss[p];
  uint32_t b = min(s >> 17, (uint32_t)(SB - 1));
  uint32_t st = sboff[b], cnt = bh[b];
  int r = (int)st;
  for (uint32_t q = st; q < st + cnt; ++q) r += (ss[q] > s) ? 1 : 0;
  if (r < MAXV) {
    uint32_t key = KEYMASK - (s & KEYMASK);
    sel_key[r] = (int)key;
    sel_cnt[r] = s >> 25;
    atomicOr(&selbm[key >> 5], 1u << (key & 31));
    unsigned long long pack = ((unsigned long long)(uint32_t)r << 32) | key;
    uint32_t slot = keyhash(key);
    while (true) {
      unsigned long long old = atomicCAS(&tab[slot & TMASK], TEMPTY, pack);
      if (old == TEMPTY) break;
      ++slot;
    }
  }
}

// ---- K6: coords + num outputs ----
__global__ void k_meta(const int* __restrict__ sel_key, const uint32_t* __restrict__ sel_cnt,
                       float* __restrict__ coords_out, float* __restrict__ num_out) {
  int id = blockIdx.x * blockDim.x + threadIdx.x;
  if (id >= MAXV) return;
  int key = sel_key[id];
  if (key < 0) return;
  int ix = key / GYZ;
  int iy = (key / GZ_K) % GY_K;
  int iz = key % GZ_K;
  coords_out[id * 3 + 0] = (float)ix;
  coords_out[id * 3 + 1] = (float)iy;
  coords_out[id * 3 + 2] = (float)iz;
  num_out[id] = (float)min(sel_cnt[id], (uint32_t)MAXP);
}

// ---- K7: scatter — bitmap pre-filter then hash lookup ----
__global__ void k_scatter(const uint32_t* __restrict__ keys,
                          const uint32_t* __restrict__ selbm,
                          const unsigned long long* __restrict__ tab,
                          int* __restrict__ vcnt, int* __restrict__ slots, int N) {
  int i = blockIdx.x * blockDim.x + threadIdx.x;
  if (i >= N) return;
  uint32_t key = keys[i];
  if (key >= KCELLS) key = KCELLS - 1;   // jnp gather clip
  if (!((selbm[key >> 5] >> (key & 31)) & 1u)) return;   // 98.4% early-out
  uint32_t slot = keyhash(key);
  int id = -1;
  while (true) {
    unsigned long long v = tab[slot & TMASK];
    if (v == TEMPTY) break;
    if ((uint32_t)v == key) { id = (int)(v >> 32); break; }
    ++slot;
  }
  if (id >= 0) {
    int slotp = atomicAdd(&vcnt[id], 1);
    if (slotp < MAXP) slots[id * MAXP + slotp] = i;
  }
}

// ---- K8: stable per-voxel rank + emit ----
__global__ void k_emit(const float4* __restrict__ pts, const int* __restrict__ vcnt,
                       const int* __restrict__ slots, float4* __restrict__ vox) {
  int vid = blockIdx.x * 8 + (threadIdx.x >> 5);
  int lane = threadIdx.x & 31;
  __shared__ int sidx[256];
  int idx = INT_MAX;
  int n = 0;
  if (vid < MAXV) {
    n = min(vcnt[vid], MAXP);
    if (lane < n) idx = slots[vid * MAXP + lane];
  }
  sidx[threadIdx.x] = idx;
  __syncthreads();
  if (vid < MAXV && lane < n) {
    int rank = 0;
    int gbase = (threadIdx.x >> 5) << 5;
    for (int j = 0; j < 32; ++j) rank += (sidx[gbase + j] < idx) ? 1 : 0;
    vox[vid * MAXP + rank] = pts[idx];
  }
}

extern "C" void kernel_launch(void* const* d_in, const int* in_sizes, int n_in,
                              void* d_out, int out_size, void* d_ws, size_t ws_size,
                              hipStream_t stream) {
  const float4* pts = (const float4*)d_in[0];
  const int N = in_sizes[0] / 4;
  const int nblk = (N + PCHUNK - 1) / PCHUNK;

  float* out = (float*)d_out;
  float* coords_out = out + (size_t)MAXV * MAXP * 4;
  float* num_out = coords_out + (size_t)MAXV * 3;

  uint8_t* wsb = (uint8_t*)d_ws;
  size_t off = 0;
  auto take = [&](size_t bytes) -> uint8_t* {
    uint8_t* p = wsb + off;
    off = (off + bytes + 255) & ~(size_t)255;
    return p;
  };
  uint32_t* keys = (uint32_t*)take((size_t)N * 4);               // 16 MB
  uint32_t* bkeys = (uint32_t*)take((size_t)N * 4);              // 16 MB
  uint32_t* stable = (uint32_t*)take((size_t)nblk * (NB + 1) * 4); // ~2 MB
  uint32_t* totals = (uint32_t*)take(NCLS * 4);
  int* ctrl = (int*)take(64);                                    // [2]=ncand [4]=ncand2
  uint32_t* cand2 = (uint32_t*)take((size_t)CAND2CAP * 4);       // 4 MB
  uint32_t* cand = (uint32_t*)take((size_t)CANDCAP * 4);         // 2 MB
  uint32_t* ss = (uint32_t*)take((size_t)CANDCAP * 4);           // 2 MB
  uint32_t* bh = (uint32_t*)take(SB * 4);
  uint32_t* sboff = (uint32_t*)take(SB * 4);
  uint32_t* scur = (uint32_t*)take(SB * 4);
  unsigned long long* tab = (unsigned long long*)take((size_t)TSIZE * 8);  // 512 KB
  uint32_t* selbm = (uint32_t*)take((size_t)BMWORDS * 4);        // 2.74 MB
  int* sel_key = (int*)take((size_t)MAXV * 4);
  uint32_t* sel_cnt = (uint32_t*)take((size_t)MAXV * 4);
  int* vcnt = (int*)take((size_t)MAXV * 4);
  int* slots = (int*)take((size_t)MAXV * MAXP * 4);              // 2.56 MB
  (void)ws_size;  // ~49 MB total

  hipMemsetAsync(totals, 0, NCLS * 4, stream);
  hipMemsetAsync(ctrl, 0, 64, stream);
  hipMemsetAsync(bh, 0, SB * 4, stream);
  hipMemsetAsync(tab, 0xFF, (size_t)TSIZE * 8, stream);
  hipMemsetAsync(selbm, 0, (size_t)BMWORDS * 4, stream);
  hipMemsetAsync(vcnt, 0, (size_t)MAXV * 4, stream);
  hipMemsetAsync(sel_key, 0xFF, (size_t)MAXV * 4, stream);
  hipMemsetAsync(d_out, 0, (size_t)out_size * sizeof(float), stream);

  k_kp<<<nblk, PTH, 0, stream>>>(pts, N, keys, bkeys, stable);
  k_bhist<<<NB, 512, 0, stream>>>(bkeys, stable, nblk, totals, cand2, &ctrl[4]);
  k_thr<<<1, 64, 0, stream>>>(totals, ctrl);
  k_collect2<<<64, 256, 0, stream>>>(cand2, &ctrl[4], ctrl, cand, &ctrl[2]);
  k_bh1<<<32, 256, 0, stream>>>(cand, &ctrl[2], bh);
  k_bscan2<<<1, 1024, 0, stream>>>(bh, sboff, scur);
  k_place<<<CANDCAP / 256, 256, 0, stream>>>(cand, &ctrl[2], sboff, scur, ss);
  k_rank2<<<CANDCAP / 256, 256, 0, stream>>>(ss, &ctrl[2], sboff, bh, tab, selbm, sel_key, sel_cnt);
  k_meta<<<(MAXV + 255) / 256, 256, 0, stream>>>(sel_key, sel_cnt, coords_out, num_out);
  k_scatter<<<(N + 255) / 256, 256, 0, stream>>>(keys, selbm, tab, vcnt, slots, N);
  k_emit<<<(MAXV + 7) / 8, 256, 0, stream>>>(pts, vcnt, slots, (float4*)out);
}

// Round 28
// 158.467 us; speedup vs baseline: 1.2915x; 1.1218x over previous
//
#include <hip/hip_runtime.h>
#include <stdint.h>
#include <limits.h>

// VERIFIED SEMANTICS (r16, absmax=0):
//  - GRID from module-level numpy f32 floor-divide: (704, 799, 39)
//  - keys: f32 sub, * 10.0f (XLA reciprocal of 0.1f), floorf, cast
//  - scatter-add drops OOB keys; gather clamps; tie-break = key ascending
#define GYZ 31161          // 799*39
#define GY_K 799
#define GZ_K 39
#define KCELLS 21937344    // 704 * 799 * 39
#define MAXV 20000
#define MAXP 32

#define NCLS 32
#define CANDCAP 524288
#define CAND2CAP 1048576
#define KEYMASK 0x1FFFFFFu // 2^25-1; KCELLS < 2^25
#define LCAP 4096
#define TSIZE 65536        // hash table slots (u64), load 0.3
#define TMASK 65535
#define TEMPTY 0xFFFFFFFFFFFFFFFFull
#define BMWORDS ((KCELLS + 31) / 32)   // selection bitmap words (2.74 MB)

#define NB 1024            // partition buckets (cell-space)
#define BUCKSZ 21424       // cells/bucket; NB*BUCKSZ >= KCELLS
#define WPB (BUCKSZ / 4)   // 5356 LDS words (21.4 KB)
#define PCHUNK 8192        // points per partition block
#define PTH 512
#define PPT (PCHUNK / PTH) // 16 keys per thread
#define DLCAP 1024         // k_bhist per-block cand buffer
#define NSEG 512           // segment-table tile in k_bhist (nblk=489 fits)

#define SB 4096            // s-value ranking buckets (s >> 17)

__device__ __forceinline__ int point_key(float x, float y, float z) {
  int ix = (int)floorf((x - 0.0f) * 10.0f);
  int iy = (int)floorf((y + 40.0f) * 10.0f);
  int iz = (int)floorf((z + 3.0f) * 10.0f);
  return (ix * GY_K + iy) * GZ_K + iz;
}

__device__ __forceinline__ uint32_t keyhash(uint32_t key) {
  return (key * 2654435761u) >> 16;
}

// ---- A: fused keys + block-contiguous partition ----
__global__ __launch_bounds__(512) void k_kp(const float4* __restrict__ pts, int N,
                                            uint32_t* __restrict__ keys,
                                            uint32_t* __restrict__ bkeys,
                                            uint32_t* __restrict__ stable) {
  __shared__ uint32_t sk[PCHUNK];       // 32 KB staging
  __shared__ uint32_t lh[NB], lb[NB], cur[NB];
  __shared__ uint32_t wsum[8];
  int blk = blockIdx.x;
  int c0 = blk * PCHUNK;
  int m = min(PCHUNK, N - c0);
  if (m <= 0) return;
  for (int j = threadIdx.x; j < NB; j += PTH) lh[j] = 0;
  __syncthreads();
  uint32_t kreg[PPT];
#pragma unroll
  for (int j = 0; j < PPT; ++j) {
    int idx = j * PTH + threadIdx.x;    // coalesced
    if (idx < m) {
      float4 p = pts[c0 + idx];
      uint32_t key = (uint32_t)point_key(p.x, p.y, p.z);
      kreg[j] = key;
      keys[c0 + idx] = key;
      atomicAdd(&lh[min(key / BUCKSZ, (uint32_t)(NB - 1))], 1u);
    } else kreg[j] = 0xFFFFFFFFu;
  }
  __syncthreads();
  // exclusive scan over 1024 buckets (2 per thread)
  int t = threadIdx.x;
  uint32_t v0 = lh[2 * t], v1 = lh[2 * t + 1];
  uint32_t s = v0 + v1;
  uint32_t incl = s;
#pragma unroll
  for (int d = 1; d < 64; d <<= 1) {
    uint32_t up = __shfl_up(incl, d);
    if ((t & 63) >= d) incl += up;
  }
  int wave = t >> 6;
  if ((t & 63) == 63) wsum[wave] = incl;
  __syncthreads();
  if (t == 0) {
    uint32_t run = 0;
    for (int w = 0; w < 8; ++w) { uint32_t tmp = wsum[w]; wsum[w] = run; run += tmp; }
  }
  __syncthreads();
  uint32_t excl = wsum[wave] + incl - s;
  lb[2 * t] = excl;          lb[2 * t + 1] = excl + v0;
  cur[2 * t] = excl;         cur[2 * t + 1] = excl + v0;
  size_t tb = (size_t)blk * (NB + 1);
  stable[tb + 2 * t] = (uint32_t)c0 + excl;
  stable[tb + 2 * t + 1] = (uint32_t)c0 + excl + v0;
  if (t == 0) stable[tb + NB] = (uint32_t)(c0 + m);
  __syncthreads();
#pragma unroll
  for (int j = 0; j < PPT; ++j) {
    uint32_t key = kreg[j];
    if (key != 0xFFFFFFFFu) {
      uint32_t b = min(key / BUCKSZ, (uint32_t)(NB - 1));
      sk[atomicAdd(&cur[b], 1u)] = key;
    }
  }
  __syncthreads();
  for (int j = threadIdx.x; j < m; j += PTH) bkeys[c0 + j] = sk[j];  // contiguous
}

// ---- D: per-bucket LDS histogram, flattened cooperative gather ----
__global__ __launch_bounds__(512) void k_bhist(const uint32_t* __restrict__ bkeys,
                                               const uint32_t* __restrict__ stable,
                                               int nblk,
                                               uint32_t* __restrict__ totals,
                                               uint32_t* __restrict__ cand2,
                                               int* __restrict__ ncand2) {
  __shared__ uint32_t lw[WPB];
  __shared__ uint32_t lt[NCLS];
  __shared__ uint32_t lbuf[DLCAP];
  __shared__ uint32_t lcnt, lbase;
  __shared__ uint32_t segs[NSEG];
  __shared__ uint32_t pfx[NSEG + 1];
  __shared__ uint32_t wsum[8];
  int b = blockIdx.x;
  int t = threadIdx.x;
  for (int w = t; w < WPB; w += 512) lw[w] = 0;
  if (t < NCLS) lt[t] = 0;
  if (t == 0) lcnt = 0;
  __syncthreads();
  uint32_t base = (uint32_t)b * BUCKSZ;
  for (int s0 = 0; s0 < nblk; s0 += NSEG) {
    int nseg = min(NSEG, nblk - s0);
    uint32_t len = 0;
    if (t < nseg) {
      size_t tb = (size_t)(s0 + t) * (NB + 1);
      uint32_t s = stable[tb + b];
      uint32_t e = stable[tb + b + 1];
      segs[t] = s;
      len = e - s;
    }
    uint32_t incl = len;
#pragma unroll
    for (int d = 1; d < 64; d <<= 1) {
      uint32_t up = __shfl_up(incl, d);
      if ((t & 63) >= d) incl += up;
    }
    int wave = t >> 6;
    if ((t & 63) == 63) wsum[wave] = incl;
    __syncthreads();
    if (t == 0) {
      uint32_t run = 0;
      for (int w = 0; w < 8; ++w) { uint32_t tmp = wsum[w]; wsum[w] = run; run += tmp; }
    }
    __syncthreads();
    uint32_t excl = wsum[wave] + incl - len;
    if (t < nseg) pfx[t] = excl;
    if (t == nseg - 1 || (t == 511 && nseg == 512)) pfx[nseg] = excl + len;
    __syncthreads();
    uint32_t L = pfx[nseg];
    for (uint32_t idx = t; idx < L; idx += 512) {
      int lo = 0, hi = nseg;
      while (hi - lo > 1) { int mid = (lo + hi) >> 1; if (pfx[mid] <= idx) lo = mid; else hi = mid; }
      uint32_t k = bkeys[segs[lo] + (idx - pfx[lo])];
      if (k < KCELLS) {
        uint32_t off = k - base;
        atomicAdd(&lw[off >> 2], 1u << ((off & 3) * 8));
      }
    }
    __syncthreads();
  }
  for (int w = t; w < WPB; w += 512) {
    uint32_t word = lw[w];
    if (!word) continue;
#pragma unroll
    for (int eb = 0; eb < 4; ++eb) {
      uint32_t v = (word >> (eb * 8)) & 0xFFu;
      if (v) {
        atomicAdd(&lt[min(v, 31u)], 1u);
        if (v >= 2u) {
          uint32_t sv = (min(v, 127u) << 25) | (KEYMASK - (base + (uint32_t)(w * 4 + eb)));
          uint32_t pos = atomicAdd(&lcnt, 1u);
          if (pos < DLCAP) lbuf[pos] = sv;
          else { int gp = atomicAdd(ncand2, 1); if (gp < CAND2CAP) cand2[gp] = sv; }
        }
      }
    }
  }
  __syncthreads();
  uint32_t cnt = min(lcnt, (uint32_t)DLCAP);
  if (t == 0) lbase = (uint32_t)atomicAdd(ncand2, (int)cnt);
  __syncthreads();
  for (uint32_t j = t; j < cnt; j += 512)
    if (lbase + j < CAND2CAP) cand2[lbase + j] = lbuf[j];
  __syncthreads();
  if (t < NCLS && lt[t]) atomicAdd(&totals[t], lt[t]);
}

// ---- K3: threshold T ----
__global__ void k_thr(const uint32_t* __restrict__ totals, int* __restrict__ ctrl) {
  if (threadIdx.x != 0 || blockIdx.x != 0) return;
  int suffix[NCLS];
  suffix[NCLS - 1] = 0;
  for (int c = NCLS - 2; c >= 0; --c) suffix[c] = suffix[c + 1] + (int)totals[c + 1];
  int T = NCLS - 1;
  for (int c = 1; c < NCLS; ++c) { if (suffix[c] <= MAXV) { T = c; break; } }
  ctrl[0] = T;
}

// ---- K4: filter cand2 by count >= T ----
__global__ __launch_bounds__(256) void k_collect2(const uint32_t* __restrict__ cand2,
                                                  const int* __restrict__ nc2_p,
                                                  const int* __restrict__ ctrl,
                                                  uint32_t* __restrict__ cand,
                                                  int* __restrict__ ncand) {
  __shared__ uint32_t lbuf[LCAP];
  __shared__ uint32_t lcnt, lbase;
  if (threadIdx.x == 0) lcnt = 0;
  __syncthreads();
  uint32_t T = (uint32_t)ctrl[0];
  int n2 = min(*nc2_p, CAND2CAP);
  int stride = gridDim.x * blockDim.x;
  for (int i = blockIdx.x * blockDim.x + threadIdx.x; i < n2; i += stride) {
    uint32_t sv = cand2[i];
    if ((sv >> 25) >= T) {
      uint32_t pos = atomicAdd(&lcnt, 1u);
      if (pos < LCAP) lbuf[pos] = sv;
      else { int gp = atomicAdd(ncand, 1); if (gp < CANDCAP) cand[gp] = sv; }
    }
  }
  __syncthreads();
  uint32_t cnt = min(lcnt, (uint32_t)LCAP);
  if (threadIdx.x == 0) lbase = (uint32_t)atomicAdd(ncand, (int)cnt);
  __syncthreads();
  for (uint32_t j = threadIdx.x; j < cnt; j += 256)
    if (lbase + j < CANDCAP) cand[lbase + j] = lbuf[j];
}

// ---- R1: s-bucket histogram ----
__global__ __launch_bounds__(256) void k_bh1(const uint32_t* __restrict__ cand,
                                             const int* __restrict__ ncand_p,
                                             uint32_t* __restrict__ bh) {
  __shared__ uint32_t lh[SB];
  for (int j = threadIdx.x; j < SB; j += 256) lh[j] = 0;
  __syncthreads();
  int n = min(*ncand_p, CANDCAP);
  int stride = gridDim.x * blockDim.x;
  for (int i = blockIdx.x * blockDim.x + threadIdx.x; i < n; i += stride)
    atomicAdd(&lh[min(cand[i] >> 17, (uint32_t)(SB - 1))], 1u);
  __syncthreads();
  for (int j = threadIdx.x; j < SB; j += 256) if (lh[j]) atomicAdd(&bh[j], lh[j]);
}

// ---- R2: suffix-exclusive scan over s-buckets ----
__global__ __launch_bounds__(1024) void k_bscan2(const uint32_t* __restrict__ bh,
                                                 uint32_t* __restrict__ sboff,
                                                 uint32_t* __restrict__ scur) {
  __shared__ uint32_t wsum[16];
  int t = threadIdx.x;
  uint32_t v[4];
  uint32_t s = 0;
#pragma unroll
  for (int e = 0; e < 4; ++e) { v[e] = bh[SB - 1 - (t * 4 + e)]; s += v[e]; }
  uint32_t incl = s;
#pragma unroll
  for (int d = 1; d < 64; d <<= 1) {
    uint32_t up = __shfl_up(incl, d);
    if ((t & 63) >= d) incl += up;
  }
  int wave = t >> 6;
  if ((t & 63) == 63) wsum[wave] = incl;
  __syncthreads();
  if (t == 0) {
    uint32_t run = 0;
    for (int w = 0; w < 16; ++w) { uint32_t tmp = wsum[w]; wsum[w] = run; run += tmp; }
  }
  __syncthreads();
  uint32_t excl = wsum[wave] + incl - s;
#pragma unroll
  for (int e = 0; e < 4; ++e) {
    int b = SB - 1 - (t * 4 + e);
    sboff[b] = excl; scur[b] = 0;
    excl += v[e];
  }
}

// ---- R3: counting-sort placement ----
__global__ void k_place(const uint32_t* __restrict__ cand, const int* __restrict__ ncand_p,
                        const uint32_t* __restrict__ sboff, uint32_t* __restrict__ scur,
                        uint32_t* __restrict__ ss) {
  int n = min(*ncand_p, CANDCAP);
  int i = blockIdx.x * blockDim.x + threadIdx.x;
  if (i >= n) return;
  uint32_t s = cand[i];
  uint32_t b = min(s >> 17, (uint32_t)(SB - 1));
  uint32_t slot = sboff[b] + atomicAdd(&scur[b], 1u);
  ss[slot] = s;
}

// ---- R4: exact rank; rank<MAXV -> hash insert + bitmap + coords/num outputs ----
__global__ void k_rank2(const uint32_t* __restrict__ ss, const int* __restrict__ ncand_p,
                        const uint32_t* __restrict__ sboff, const uint32_t* __restrict__ bh,
                        unsigned long long* __restrict__ tab,
                        uint32_t* __restrict__ selbm,
                        float* __restrict__ coords_out, float* __restrict__ num_out) {
  int n = min(*ncand_p, CANDCAP);
  int p = blockIdx.x * blockDim.x + threadIdx.x;
  if (p >= n) return;
  uint32_t s = ss[p];
  uint32_t b = min(s >> 17, (uint32_t)(SB - 1));
  uint32_t st = sboff[b], cnt = bh[b];
  int r = (int)st;
  for (uint32_t q = st; q < st + cnt; ++q) r += (ss[q] > s) ? 1 : 0;
  if (r < MAXV) {
    uint32_t key = KEYMASK - (s & KEYMASK);
    atomicOr(&selbm[key >> 5], 1u << (key & 31));
    unsigned long long pack = ((unsigned long long)(uint32_t)r << 32) | key;
    uint32_t slot = keyhash(key);
    while (true) {
      unsigned long long old = atomicCAS(&tab[slot & TMASK], TEMPTY, pack);
      if (old == TEMPTY) break;
      ++slot;
    }
    // fused k_meta: coords + num (every rank 0..MAXV-1 occurs exactly once; ncand>=MAXV)
    int ix = (int)key / GYZ;
    int iy = ((int)key / GZ_K) % GY_K;
    int iz = (int)key % GZ_K;
    coords_out[r * 3 + 0] = (float)ix;
    coords_out[r * 3 + 1] = (float)iy;
    coords_out[r * 3 + 2] = (float)iz;
    num_out[r] = (float)min(s >> 25, (uint32_t)MAXP);
  }
}

// ---- K7: scatter — bitmap pre-filter then hash lookup ----
__global__ void k_scatter(const uint32_t* __restrict__ keys,
                          const uint32_t* __restrict__ selbm,
                          const unsigned long long* __restrict__ tab,
                          int* __restrict__ vcnt, int* __restrict__ slots, int N) {
  int i = blockIdx.x * blockDim.x + threadIdx.x;
  if (i >= N) return;
  uint32_t key = keys[i];
  if (key >= KCELLS) key = KCELLS - 1;   // jnp gather clip
  if (!((selbm[key >> 5] >> (key & 31)) & 1u)) return;   // 98.4% early-out
  uint32_t slot = keyhash(key);
  int id = -1;
  while (true) {
    unsigned long long v = tab[slot & TMASK];
    if (v == TEMPTY) break;
    if ((uint32_t)v == key) { id = (int)(v >> 32); break; }
    ++slot;
  }
  if (id >= 0) {
    int slotp = atomicAdd(&vcnt[id], 1);
    if (slotp < MAXP) slots[id * MAXP + slotp] = i;
  }
}

// ---- K8: stable per-voxel rank + emit (zero-fills unused slots; owns whole region) ----
__global__ void k_emit(const float4* __restrict__ pts, const int* __restrict__ vcnt,
                       const int* __restrict__ slots, float4* __restrict__ vox) {
  int vid = blockIdx.x * 8 + (threadIdx.x >> 5);
  int lane = threadIdx.x & 31;
  __shared__ int sidx[256];
  int idx = INT_MAX;
  int n = 0;
  if (vid < MAXV) {
    n = min(vcnt[vid], MAXP);
    if (lane < n) idx = slots[vid * MAXP + lane];
  }
  sidx[threadIdx.x] = idx;
  __syncthreads();
  if (vid < MAXV) {
    if (lane < n) {
      int rank = 0;
      int gbase = (threadIdx.x >> 5) << 5;
      for (int j = 0; j < 32; ++j) rank += (sidx[gbase + j] < idx) ? 1 : 0;
      vox[vid * MAXP + rank] = pts[idx];
    } else {
      vox[vid * MAXP + lane] = make_float4(0.f, 0.f, 0.f, 0.f);  // ranks n..31 unoccupied
    }
  }
}

extern "C" void kernel_launch(void* const* d_in, const int* in_sizes, int n_in,
                              void* d_out, int out_size, void* d_ws, size_t ws_size,
                              hipStream_t stream) {
  const float4* pts = (const float4*)d_in[0];
  const int N = in_sizes[0] / 4;
  const int nblk = (N + PCHUNK - 1) / PCHUNK;

  float* out = (float*)d_out;
  float* coords_out = out + (size_t)MAXV * MAXP * 4;
  float* num_out = coords_out + (size_t)MAXV * 3;

  uint8_t* wsb = (uint8_t*)d_ws;
  size_t off = 0;
  auto take = [&](size_t bytes) -> uint8_t* {
    uint8_t* p = wsb + off;
    off = (off + bytes + 255) & ~(size_t)255;
    return p;
  };
  uint32_t* keys = (uint32_t*)take((size_t)N * 4);               // 16 MB
  uint32_t* bkeys = (uint32_t*)take((size_t)N * 4);              // 16 MB
  uint32_t* stable = (uint32_t*)take((size_t)nblk * (NB + 1) * 4); // ~2 MB
  uint32_t* cand2 = (uint32_t*)take((size_t)CAND2CAP * 4);       // 4 MB
  uint32_t* cand = (uint32_t*)take((size_t)CANDCAP * 4);         // 2 MB
  uint32_t* ss = (uint32_t*)take((size_t)CANDCAP * 4);           // 2 MB
  uint32_t* sboff = (uint32_t*)take(SB * 4);
  uint32_t* scur = (uint32_t*)take(SB * 4);
  uint32_t* slotsbuf = (uint32_t*)take((size_t)MAXV * MAXP * 4); // 2.56 MB (written by scatter)
  // ---- zero-init group (ONE memset covers [z0, zend)) ----
  uint8_t* z0 = wsb + off;
  uint32_t* totals = (uint32_t*)take(NCLS * 4);
  int* ctrl = (int*)take(64);                                    // [2]=ncand [4]=ncand2
  uint32_t* bh = (uint32_t*)take(SB * 4);
  uint32_t* selbm = (uint32_t*)take((size_t)BMWORDS * 4);        // 2.74 MB
  int* vcnt = (int*)take((size_t)MAXV * 4);
  size_t zbytes = (size_t)((wsb + off) - z0);
  // ---- 0xFF-init group (ONE memset) ----
  uint8_t* f0 = wsb + off;
  unsigned long long* tab = (unsigned long long*)take((size_t)TSIZE * 8);  // 512 KB
  size_t fbytes = (size_t)((wsb + off) - f0);
  (void)ws_size;  // ~49 MB total
  int* slots = (int*)slotsbuf;

  hipMemsetAsync(z0, 0, zbytes, stream);
  hipMemsetAsync(f0, 0xFF, fbytes, stream);

  k_kp<<<nblk, PTH, 0, stream>>>(pts, N, keys, bkeys, stable);
  k_bhist<<<NB, 512, 0, stream>>>(bkeys, stable, nblk, totals, cand2, &ctrl[4]);
  k_thr<<<1, 64, 0, stream>>>(totals, ctrl);
  k_collect2<<<64, 256, 0, stream>>>(cand2, &ctrl[4], ctrl, cand, &ctrl[2]);
  k_bh1<<<32, 256, 0, stream>>>(cand, &ctrl[2], bh);
  k_bscan2<<<1, 1024, 0, stream>>>(bh, sboff, scur);
  k_place<<<CANDCAP / 256, 256, 0, stream>>>(cand, &ctrl[2], sboff, scur, ss);
  k_rank2<<<CANDCAP / 256, 256, 0, stream>>>(ss, &ctrl[2], sboff, bh, tab, selbm,
                                             coords_out, num_out);
  k_scatter<<<(N + 255) / 256, 256, 0, stream>>>(keys, selbm, tab, vcnt, slots, N);
  k_emit<<<(MAXV + 7) / 8, 256, 0, stream>>>(pts, vcnt, slots, (float4*)out);
}